// Round 1
// baseline (569.330 us; speedup 1.0000x reference)
//
#include <hip/hip_runtime.h>
#include <hip/hip_bf16.h>
#include <math.h>

// Problem constants
#define B_  4
#define T_  8192
#define H_  1024
#define NHEAD 16
#define DH  64
#define BT  (B_*T_)   // 32768 rows

typedef __attribute__((ext_vector_type(8))) short bf16x8;
typedef __attribute__((ext_vector_type(4))) float f32x4;
typedef __attribute__((ext_vector_type(2))) float f32x2;
typedef __attribute__((ext_vector_type(2))) unsigned short u16x2;
typedef __attribute__((ext_vector_type(4))) unsigned short u16x4;
typedef __attribute__((ext_vector_type(8))) unsigned short u16x8;

static __device__ __forceinline__ float bf2f(unsigned short u) {
  union { unsigned int i; float f; } x; x.i = ((unsigned int)u) << 16; return x.f;
}
static __device__ __forceinline__ unsigned short f2bf(float f) {
  union { float f; unsigned int i; } x; x.f = f;
  unsigned int r = x.i + 0x7fffu + ((x.i >> 16) & 1u);  // RNE
  return (unsigned short)(r >> 16);
}

#define GL2LDS(gptr, sptr) \
  __builtin_amdgcn_global_load_lds((const __attribute__((address_space(1))) void*)(gptr), \
                                   (__attribute__((address_space(3))) void*)(sptr), 16, 0, 0)

// ---------------------------------------------------------------- cvt fp32->bf16
__global__ void cvt_kernel(const float* __restrict__ in, unsigned short* __restrict__ out, int n4) {
  int i = blockIdx.x * blockDim.x + threadIdx.x;
  int stride = gridDim.x * blockDim.x;
  for (int idx = i; idx < n4; idx += stride) {
    float4 v = reinterpret_cast<const float4*>(in)[idx];
    u16x4 o;
    o.x = f2bf(v.x); o.y = f2bf(v.y); o.z = f2bf(v.z); o.w = f2bf(v.w);
    reinterpret_cast<u16x4*>(out)[idx] = o;
  }
}

// ---------------------------------------------------------------- bf16 NT GEMM (m97 structure)
// C[M,N] = A[M,K] * B[N,K]^T + bias ; M=32768, N=K=1024. 128x128 tile, BK=32.
__global__ __launch_bounds__(256, 2) void gemm_nt(
    const unsigned short* __restrict__ A,
    const unsigned short* __restrict__ Bm,
    const float* __restrict__ bias,
    unsigned short* __restrict__ C) {
  const int K = 1024, N = 1024;
  __shared__ unsigned short sA[128 * 32];  // 8 KB
  __shared__ unsigned short sB[128 * 32];  // 8 KB
  const int tid  = threadIdx.x;
  const int lane = tid & 63;
  const int wid  = tid >> 6;
  const int bm = blockIdx.y * 128, bn = blockIdx.x * 128;
  const int wm = (wid >> 1) * 64,  wn = (wid & 1) * 64;

  f32x4 acc[4][4];
#pragma unroll
  for (int nn = 0; nn < 4; ++nn) {
    float bv = bias[bn + wn + nn * 16 + (lane & 15)];
    f32x4 sp = {bv, bv, bv, bv};
#pragma unroll
    for (int mm = 0; mm < 4; ++mm) acc[mm][nn] = sp;
  }

  // staging: thread t loads 16B of row (t>>2), k-chunk (t&3)*8 ; 2 rounds of 64 rows per tile
  const int srow = tid >> 2;
  const int scol = (tid & 3) * 8;
  const unsigned short* gA0 = A  + (size_t)(bm + srow) * K + scol;
  const unsigned short* gA1 = gA0 + (size_t)64 * K;
  const unsigned short* gB0 = Bm + (size_t)(bn + srow) * K + scol;
  const unsigned short* gB1 = gB0 + (size_t)64 * K;
  char* dA = (char*)&sA[0] + wid * 1024;  // wave-uniform; HW adds lane*16
  char* dB = (char*)&sB[0] + wid * 1024;

  const char* fA = (const char*)&sA[0] + (wm + (lane & 15)) * 64 + (lane >> 4) * 16;
  const char* fB = (const char*)&sB[0] + (wn + (lane & 15)) * 64 + (lane >> 4) * 16;

  for (int k0 = 0; k0 < K; k0 += 32) {
    GL2LDS(gA0 + k0, dA);
    GL2LDS(gA1 + k0, dA + 4096);
    GL2LDS(gB0 + k0, dB);
    GL2LDS(gB1 + k0, dB + 4096);
    __syncthreads();   // drains vmcnt -> LDS populated
    bf16x8 av[4], bv_[4];
#pragma unroll
    for (int mm = 0; mm < 4; ++mm) av[mm]  = *(const bf16x8*)(fA + mm * 1024);
#pragma unroll
    for (int nn = 0; nn < 4; ++nn) bv_[nn] = *(const bf16x8*)(fB + nn * 1024);
#pragma unroll
    for (int mm = 0; mm < 4; ++mm)
#pragma unroll
      for (int nn = 0; nn < 4; ++nn)
        acc[mm][nn] = __builtin_amdgcn_mfma_f32_16x16x32_bf16(av[mm], bv_[nn], acc[mm][nn], 0, 0, 0);
    __syncthreads();   // protect LDS before next stage
  }

  const int crow = bm + wm + (lane >> 4) * 4;
  const int ccol = bn + wn + (lane & 15);
#pragma unroll
  for (int mm = 0; mm < 4; ++mm)
#pragma unroll
    for (int j = 0; j < 4; ++j) {
      unsigned short* cp = C + (size_t)(crow + mm * 16 + j) * N + ccol;
#pragma unroll
      for (int nn = 0; nn < 4; ++nn) cp[nn * 16] = f2bf(acc[mm][nn][j]);
    }
}

// ---------------------------------------------------------------- phase1: U-partials + colsum-partials
// grid (8 chunks, 64 nh). U[d][e] = sum_t exp(kp[t][d]+madd) * vp[t][e]
__global__ __launch_bounds__(256) void phase1(
    const unsigned short* __restrict__ Pk,
    const unsigned short* __restrict__ Pv,
    const float* __restrict__ mask_attn,
    float* __restrict__ Upart,     // [8][64][64][64]
    float* __restrict__ cspart) {  // [8][64][64]
  const int chunk = blockIdx.x;
  const int nh = blockIdx.y;
  const int n = nh >> 4, h = nh & 15;
  const int tid = threadIdx.x;
  __shared__ float ek[8][64];
  __shared__ float ev[8][64];
  __shared__ float cs[256];
  float acc[4][4] = {};
  float csa = 0.f, csb = 0.f;
  const int tl = tid >> 5;            // staged row 0..7
  const int d2 = (tid & 31) * 2;      // feature pair
  const int d0 = (tid >> 4) * 4, e0 = (tid & 15) * 4;

  for (int t8 = 0; t8 < 1024; t8 += 8) {
    const int t = chunk * 1024 + t8 + tl;
    const size_t off = (size_t)(n * T_ + t) * H_ + h * DH + d2;
    const float madd = -10000.f * (1.f - mask_attn[n * T_ + t]);
    u16x2 kk = *(const u16x2*)(Pk + off);
    u16x2 vv = *(const u16x2*)(Pv + off);
    float ea = __expf(bf2f(kk.x) + madd);
    float eb = __expf(bf2f(kk.y) + madd);
    f32x2 w0 = {ea, eb};
    f32x2 w1 = {bf2f(vv.x), bf2f(vv.y)};
    *(f32x2*)&ek[tl][d2] = w0;
    *(f32x2*)&ev[tl][d2] = w1;
    csa += ea; csb += eb;
    __syncthreads();
#pragma unroll
    for (int r = 0; r < 8; ++r) {
      f32x4 a = *(const f32x4*)&ek[r][d0];
      f32x4 b = *(const f32x4*)&ev[r][e0];
#pragma unroll
      for (int i = 0; i < 4; ++i)
#pragma unroll
        for (int j = 0; j < 4; ++j) acc[i][j] = fmaf(a[i], b[j], acc[i][j]);
    }
    __syncthreads();
  }
  float* up = Upart + ((size_t)(chunk * 64 + nh) * 64 + d0) * 64 + e0;
#pragma unroll
  for (int i = 0; i < 4; ++i)
#pragma unroll
    for (int j = 0; j < 4; ++j) up[i * 64 + j] = acc[i][j];

  cs[tid] = csa; __syncthreads();
  if (tid < 32) {
    float s = 0;
#pragma unroll
    for (int kk2 = 0; kk2 < 8; ++kk2) s += cs[tid + 32 * kk2];
    cspart[((size_t)chunk * 64 + nh) * 64 + 2 * tid] = s;
  }
  __syncthreads();
  cs[tid] = csb; __syncthreads();
  if (tid < 32) {
    float s = 0;
#pragma unroll
    for (int kk2 = 0; kk2 < 8; ++kk2) s += cs[tid + 32 * kk2];
    cspart[((size_t)chunk * 64 + nh) * 64 + 2 * tid + 1] = s;
  }
}

// ---------------------------------------------------------------- ctx build (reduce partials, store ctx^T bf16)
__global__ void ctxbuild(const float* __restrict__ Upart,
                         const float* __restrict__ cspart,
                         unsigned short* __restrict__ ctxT) {  // [64 nh][64 e][64 d]
  const int nh = blockIdx.x, tid = threadIdx.x;
  __shared__ float cs[64];
  if (tid < 64) {
    float s = 0;
    for (int c = 0; c < 8; ++c) s += cspart[((size_t)c * 64 + nh) * 64 + tid];
    cs[tid] = s;
  }
  __syncthreads();
  const int d0 = (tid >> 4) * 4, e0 = (tid & 15) * 4;
#pragma unroll
  for (int i = 0; i < 4; ++i) {
    const float inv = 0.125f / cs[d0 + i];   // 1/(sqrt(64)*colsum)
#pragma unroll
    for (int j = 0; j < 4; ++j) {
      float s = 0;
      for (int c = 0; c < 8; ++c)
        s += Upart[((size_t)(c * 64 + nh) * 64 + d0 + i) * 64 + e0 + j];
      ctxT[((size_t)nh * 64 + (e0 + j)) * 64 + (d0 + i)] = f2bf(s * inv);
    }
  }
}

// ---------------------------------------------------------------- out: softmax_feat(qp) @ ctx via MFMA
// grid (64 t-tiles of 128, 64 nh), 256 threads (4 waves x 32 rows)
__global__ __launch_bounds__(256) void outk(
    const unsigned short* __restrict__ Pq,
    const unsigned short* __restrict__ ctxT,
    float* __restrict__ Out) {
  const int tb = blockIdx.x;
  const int nh = blockIdx.y;
  const int n = nh >> 4, h = nh & 15;
  const int tid = threadIdx.x, lane = tid & 63, wid = tid >> 6;
  __shared__ unsigned short sp[128][72];   // padded: row stride 144 B

  // B fragments (ctx^T) straight from global, K=64 -> 2 k-steps x 4 n-tiles
  bf16x8 breg[2][4];
#pragma unroll
  for (int ks = 0; ks < 2; ++ks)
#pragma unroll
    for (int nn = 0; nn < 4; ++nn)
      breg[ks][nn] = *(const bf16x8*)(ctxT + ((size_t)nh * 64 + nn * 16 + (lane & 15)) * 64
                                      + ks * 32 + (lane >> 4) * 8);

  // stage: thread handles row r = tid>>1, half = tid&1 (32 features)
  const int r = tid >> 1, half = tid & 1;
  const int t0 = tb * 128;
  const size_t qoff = (size_t)(n * T_ + t0 + r) * H_ + h * DH + half * 32;
  u16x8 qv[4];
#pragma unroll
  for (int s = 0; s < 4; ++s) qv[s] = *(const u16x8*)(Pq + qoff + s * 8);
  float e[32]; float sum = 0.f;
#pragma unroll
  for (int s = 0; s < 4; ++s)
#pragma unroll
    for (int j = 0; j < 8; ++j) { float x = __expf(bf2f(qv[s][j])); e[s * 8 + j] = x; sum += x; }
  sum += __shfl_xor(sum, 1);               // full 64-feature row sum
  const float inv = 1.f / sum;
#pragma unroll
  for (int s = 0; s < 4; ++s) {
    u16x8 pb;
#pragma unroll
    for (int j = 0; j < 8; ++j) pb[j] = f2bf(e[s * 8 + j] * inv);
    *(u16x8*)&sp[r][half * 32 + s * 8] = pb;
  }
  __syncthreads();

  f32x4 acc[2][4];
  f32x4 z = {0.f, 0.f, 0.f, 0.f};
#pragma unroll
  for (int mm = 0; mm < 2; ++mm)
#pragma unroll
    for (int nn = 0; nn < 4; ++nn) acc[mm][nn] = z;
  const int wm = wid * 32;
#pragma unroll
  for (int ks = 0; ks < 2; ++ks) {
    bf16x8 av[2];
#pragma unroll
    for (int mm = 0; mm < 2; ++mm)
      av[mm] = *(const bf16x8*)((const char*)&sp[0][0]
               + (wm + mm * 16 + (lane & 15)) * 144 + ks * 64 + (lane >> 4) * 16);
#pragma unroll
    for (int mm = 0; mm < 2; ++mm)
#pragma unroll
      for (int nn = 0; nn < 4; ++nn)
        acc[mm][nn] = __builtin_amdgcn_mfma_f32_16x16x32_bf16(av[mm], breg[ks][nn], acc[mm][nn], 0, 0, 0);
  }

#pragma unroll
  for (int mm = 0; mm < 2; ++mm)
#pragma unroll
    for (int j = 0; j < 4; ++j) {
      const int row = t0 + wm + mm * 16 + (lane >> 4) * 4 + j;
      float* op = Out + ((size_t)n * T_ + row) * H_ + h * DH + (lane & 15);
#pragma unroll
      for (int nn = 0; nn < 4; ++nn) op[nn * 16] = acc[mm][nn][j];
    }
}

// ---------------------------------------------------------------- launch
extern "C" void kernel_launch(void* const* d_in, const int* in_sizes, int n_in,
                              void* d_out, int out_size, void* d_ws, size_t ws_size,
                              hipStream_t stream) {
  const float* q  = (const float*)d_in[0];
  const float* k  = (const float*)d_in[1];
  const float* v  = (const float*)d_in[2];
  // d_in[3] = mask_q: per-row constant before feature-dim softmax -> provably a no-op
  const float* mask_attn = (const float*)d_in[4];
  const float* Wq = (const float*)d_in[5];
  const float* bq = (const float*)d_in[6];
  const float* Wk = (const float*)d_in[7];
  const float* bk = (const float*)d_in[8];
  const float* Wv = (const float*)d_in[9];
  const float* bv = (const float*)d_in[10];
  float* out = (float*)d_out;

  char* ws = (char*)d_ws;
  size_t off = 0;
  unsigned short* Xb = (unsigned short*)(ws + off); off += (size_t)BT * H_ * 2;       // 64 MB
  unsigned short* Wb = (unsigned short*)(ws + off); off += (size_t)3 * H_ * H_ * 2;   // 6 MB
  unsigned short* Pq = (unsigned short*)(ws + off); off += (size_t)BT * H_ * 2;
  unsigned short* Pk = (unsigned short*)(ws + off); off += (size_t)BT * H_ * 2;
  unsigned short* Pv = (unsigned short*)(ws + off); off += (size_t)BT * H_ * 2;
  float* Upart  = (float*)(ws + off); off += (size_t)8 * 64 * 64 * 64 * 4;            // 8 MB
  float* cspart = (float*)(ws + off); off += (size_t)8 * 64 * 64 * 4;
  unsigned short* ctxT = (unsigned short*)(ws + off); off += (size_t)64 * 64 * 64 * 2;

  dim3 blk(256);
  const int nW4 = H_ * H_ / 4;
  cvt_kernel<<<dim3(512), blk, 0, stream>>>(Wq, Wb + 0 * H_ * H_, nW4);
  cvt_kernel<<<dim3(512), blk, 0, stream>>>(Wk, Wb + 1 * H_ * H_, nW4);
  cvt_kernel<<<dim3(512), blk, 0, stream>>>(Wv, Wb + 2 * H_ * H_, nW4);

  const int nX4 = BT * H_ / 4;
  dim3 ggrid(8, 256);   // N/128, M/128
  cvt_kernel<<<dim3(2048), blk, 0, stream>>>(k, Xb, nX4);
  gemm_nt<<<ggrid, blk, 0, stream>>>(Xb, Wb + 1 * H_ * H_, bk, Pk);
  cvt_kernel<<<dim3(2048), blk, 0, stream>>>(v, Xb, nX4);
  gemm_nt<<<ggrid, blk, 0, stream>>>(Xb, Wb + 2 * H_ * H_, bv, Pv);
  cvt_kernel<<<dim3(2048), blk, 0, stream>>>(q, Xb, nX4);
  gemm_nt<<<ggrid, blk, 0, stream>>>(Xb, Wb + 0 * H_ * H_, bq, Pq);

  phase1<<<dim3(8, 64), blk, 0, stream>>>(Pk, Pv, mask_attn, Upart, cspart);
  ctxbuild<<<dim3(64), blk, 0, stream>>>(Upart, cspart, ctxT);
  outk<<<dim3(64, 64), blk, 0, stream>>>(Pq, ctxT, out);
}

// Round 2
// 446.993 us; speedup vs baseline: 1.2737x; 1.2737x over previous
//
#include <hip/hip_runtime.h>
#include <hip/hip_bf16.h>
#include <math.h>

// Problem constants
#define B_  4
#define T_  8192
#define H_  1024
#define NHEAD 16
#define DH  64
#define BT  (B_*T_)   // 32768 rows

typedef __attribute__((ext_vector_type(8))) short bf16x8;
typedef __attribute__((ext_vector_type(4))) float f32x4;
typedef __attribute__((ext_vector_type(2))) float f32x2;
typedef __attribute__((ext_vector_type(2))) unsigned short u16x2;
typedef __attribute__((ext_vector_type(4))) unsigned short u16x4;
typedef __attribute__((ext_vector_type(8))) unsigned short u16x8;

static __device__ __forceinline__ float bf2f(unsigned short u) {
  union { unsigned int i; float f; } x; x.i = ((unsigned int)u) << 16; return x.f;
}
static __device__ __forceinline__ unsigned short f2bf(float f) {
  union { float f; unsigned int i; } x; x.f = f;
  unsigned int r = x.i + 0x7fffu + ((x.i >> 16) & 1u);  // RNE
  return (unsigned short)(r >> 16);
}

#define GL2LDS(gptr, sptr) \
  __builtin_amdgcn_global_load_lds((const __attribute__((address_space(1))) void*)(gptr), \
                                   (__attribute__((address_space(3))) void*)(sptr), 16, 0, 0)

// ---------------------------------------------------------------- cvt fp32->bf16
__global__ void cvt_kernel(const float* __restrict__ in, unsigned short* __restrict__ out, int n4) {
  int i = blockIdx.x * blockDim.x + threadIdx.x;
  int stride = gridDim.x * blockDim.x;
  for (int idx = i; idx < n4; idx += stride) {
    float4 v = reinterpret_cast<const float4*>(in)[idx];
    u16x4 o;
    o.x = f2bf(v.x); o.y = f2bf(v.y); o.z = f2bf(v.z); o.w = f2bf(v.w);
    reinterpret_cast<u16x4*>(out)[idx] = o;
  }
}

// ---------------------------------------------------------------- bf16 NT GEMM (m97 structure)
// C[M,N] = A[M,K] * B[N,K]^T + bias ; M=32768, N=K=1024. 128x128 tile, BK=32.
// grid must be (8, 256) -> 2048 blocks; XCD swizzle assumes nwg=2048, 8 XCDs.
__global__ __launch_bounds__(256, 2) void gemm_nt(
    const unsigned short* __restrict__ A,
    const unsigned short* __restrict__ Bm,
    const float* __restrict__ bias,
    unsigned short* __restrict__ C) {
  const int K = 1024, N = 1024;
  __shared__ unsigned short sA[128 * 32];  // 8 KB
  __shared__ unsigned short sB[128 * 32];  // 8 KB
  const int tid  = threadIdx.x;
  const int lane = tid & 63;
  const int wid  = tid >> 6;
  // XCD-aware swizzle (T1): hw-consecutive blocks round-robin XCDs; give each
  // XCD 256 consecutive logical tiles = 32 full M-rows so the 8 N-blocks that
  // share an A-panel stay in one XCD's L2.
  const int orig = blockIdx.y * 8 + blockIdx.x;
  const int swz  = (orig & 7) * 256 + (orig >> 3);
  const int bm = (swz >> 3) * 128, bn = (swz & 7) * 128;
  const int wm = (wid >> 1) * 64,  wn = (wid & 1) * 64;

  f32x4 acc[4][4];
#pragma unroll
  for (int nn = 0; nn < 4; ++nn) {
    float bv = bias[bn + wn + nn * 16 + (lane & 15)];
    f32x4 sp = {bv, bv, bv, bv};
#pragma unroll
    for (int mm = 0; mm < 4; ++mm) acc[mm][nn] = sp;
  }

  // staging: thread t loads 16B of row (t>>2), k-chunk (t&3)*8 ; 2 rounds of 64 rows per tile
  const int srow = tid >> 2;
  const int scol = (tid & 3) * 8;
  const unsigned short* gA0 = A  + (size_t)(bm + srow) * K + scol;
  const unsigned short* gA1 = gA0 + (size_t)64 * K;
  const unsigned short* gB0 = Bm + (size_t)(bn + srow) * K + scol;
  const unsigned short* gB1 = gB0 + (size_t)64 * K;
  char* dA = (char*)&sA[0] + wid * 1024;  // wave-uniform; HW adds lane*16
  char* dB = (char*)&sB[0] + wid * 1024;

  const char* fA = (const char*)&sA[0] + (wm + (lane & 15)) * 64 + (lane >> 4) * 16;
  const char* fB = (const char*)&sB[0] + (wn + (lane & 15)) * 64 + (lane >> 4) * 16;

  for (int k0 = 0; k0 < K; k0 += 32) {
    GL2LDS(gA0 + k0, dA);
    GL2LDS(gA1 + k0, dA + 4096);
    GL2LDS(gB0 + k0, dB);
    GL2LDS(gB1 + k0, dB + 4096);
    __syncthreads();   // drains vmcnt -> LDS populated
    bf16x8 av[4], bv_[4];
#pragma unroll
    for (int mm = 0; mm < 4; ++mm) av[mm]  = *(const bf16x8*)(fA + mm * 1024);
#pragma unroll
    for (int nn = 0; nn < 4; ++nn) bv_[nn] = *(const bf16x8*)(fB + nn * 1024);
#pragma unroll
    for (int mm = 0; mm < 4; ++mm)
#pragma unroll
      for (int nn = 0; nn < 4; ++nn)
        acc[mm][nn] = __builtin_amdgcn_mfma_f32_16x16x32_bf16(av[mm], bv_[nn], acc[mm][nn], 0, 0, 0);
    __syncthreads();   // protect LDS before next stage
  }

  const int crow = bm + wm + (lane >> 4) * 4;
  const int ccol = bn + wn + (lane & 15);
#pragma unroll
  for (int mm = 0; mm < 4; ++mm)
#pragma unroll
    for (int j = 0; j < 4; ++j) {
      unsigned short* cp = C + (size_t)(crow + mm * 16 + j) * N + ccol;
#pragma unroll
      for (int nn = 0; nn < 4; ++nn) cp[nn * 16] = f2bf(acc[mm][nn][j]);
    }
}

// ---------------------------------------------------------------- phase1 (MFMA): U-partials + colsum
// grid (8 chunks, 64 nh), 256 threads. Per block: chunk of 1024 t's, one head.
// U[d][e] = sum_t exp(kp[t][d]+madd)*vp[t][e]; cs[d] = sum_t exp(kp[t][d]+madd).
// LDS: ekT[64][256], vpT[64][256] (feature-major, XOR-swizzled rows of 512B).
__global__ __launch_bounds__(256, 2) void phase1(
    const unsigned short* __restrict__ Pk,
    const unsigned short* __restrict__ Pv,
    const float* __restrict__ mask_attn,
    float* __restrict__ Upart,     // [8][64][64][64]
    float* __restrict__ cspart) {  // [8][64][64]
  const int chunk = blockIdx.x;
  const int nh = blockIdx.y;
  const int n = nh >> 4, h = nh & 15;
  const int tid = threadIdx.x, lane = tid & 63, wid = tid >> 6;
  __shared__ __align__(16) unsigned short ekT[64 * 256];  // 32 KB
  __shared__ __align__(16) unsigned short vpT[64 * 256];  // 32 KB

  f32x4 acc[5];  // 4 e-tiles + colsum (ones-B trick)
#pragma unroll
  for (int i = 0; i < 5; ++i) acc[i] = (f32x4){0.f, 0.f, 0.f, 0.f};
  bf16x8 ones;
#pragma unroll
  for (int j = 0; j < 8; ++j) ones[j] = (short)0x3f80;  // 1.0 bf16

  const int isV = tid >> 7;            // threads 0..127: Pk(+exp), 128..255: Pv
  const int slot0 = tid & 127;
  const unsigned short* src = isV ? Pv : Pk;
  unsigned short* dstT = isV ? vpT : ekT;

  const int arow = wid * 16 + (lane & 15);
  const int aswz = ((arow & 7) ^ ((arow >> 3) & 7)) << 4;

  for (int stage = 0; stage < 4; ++stage) {
    if (stage) __syncthreads();        // LDS consumed by previous mfma phase
#pragma unroll
    for (int r = 0; r < 2; ++r) {
      const int slot = slot0 + r * 128;          // 0..255
      const int toct = slot >> 3;                // 0..31
      const int d0   = (slot & 7) * 8;
      const int tbase = chunk * 1024 + stage * 256 + toct * 8;
      u16x8 in[8];
#pragma unroll
      for (int s = 0; s < 8; ++s)
        in[s] = *(const u16x8*)(src + (size_t)(n * T_ + tbase + s) * H_ + h * DH + d0);
      if (!isV) {
#pragma unroll
        for (int s = 0; s < 8; ++s) {
          const float madd = -10000.f * (1.f - mask_attn[n * T_ + tbase + s]);
          u16x8 o;
#pragma unroll
          for (int j = 0; j < 8; ++j) o[j] = f2bf(__expf(bf2f(in[s][j]) + madd));
          in[s] = o;
        }
      }
      // 8x8 in-register transpose, then one b128 write per feature row
#pragma unroll
      for (int i = 0; i < 8; ++i) {
        u16x8 o;
#pragma unroll
        for (int s = 0; s < 8; ++s) o[s] = in[s][i];
        const int d = d0 + i;
        const int boff = (toct * 16) ^ (((d & 7) ^ ((d >> 3) & 7)) << 4);
        *(u16x8*)((char*)dstT + d * 512 + boff) = o;
      }
    }
    __syncthreads();
    // MFMA: 8 k-steps of 32 t's
#pragma unroll
    for (int kk = 0; kk < 8; ++kk) {
      const int koff = kk * 64 + (lane >> 4) * 16;
      bf16x8 af = *(const bf16x8*)((const char*)ekT + arow * 512 + (koff ^ aswz));
      acc[4] = __builtin_amdgcn_mfma_f32_16x16x32_bf16(af, ones, acc[4], 0, 0, 0);
#pragma unroll
      for (int nn = 0; nn < 4; ++nn) {
        const int brow = nn * 16 + (lane & 15);
        const int bswz = ((brow & 7) ^ ((brow >> 3) & 7)) << 4;
        bf16x8 bf_ = *(const bf16x8*)((const char*)vpT + brow * 512 + (koff ^ bswz));
        acc[nn] = __builtin_amdgcn_mfma_f32_16x16x32_bf16(af, bf_, acc[nn], 0, 0, 0);
      }
    }
  }

  // epilogue: acc[nn][j] = U[d = wid*16+(lane>>4)*4+j][e = nn*16+(lane&15)]
  const int d = wid * 16 + (lane >> 4) * 4;
  const int e = lane & 15;
  float* up = Upart + ((size_t)(chunk * 64 + nh) * 64) * 64;
#pragma unroll
  for (int nn = 0; nn < 4; ++nn)
#pragma unroll
    for (int j = 0; j < 4; ++j)
      up[(size_t)(d + j) * 64 + nn * 16 + e] = acc[nn][j];
  if (e == 0)
#pragma unroll
    for (int j = 0; j < 4; ++j)
      cspart[((size_t)chunk * 64 + nh) * 64 + d + j] = acc[4][j];
}

// ---------------------------------------------------------------- ctx build (reduce partials, store ctx^T bf16)
__global__ void ctxbuild(const float* __restrict__ Upart,
                         const float* __restrict__ cspart,
                         unsigned short* __restrict__ ctxT) {  // [64 nh][64 e][64 d]
  const int nh = blockIdx.x, tid = threadIdx.x;
  __shared__ float cs[64];
  if (tid < 64) {
    float s = 0;
    for (int c = 0; c < 8; ++c) s += cspart[((size_t)c * 64 + nh) * 64 + tid];
    cs[tid] = s;
  }
  __syncthreads();
  const int d0 = (tid >> 4) * 4, e0 = (tid & 15) * 4;
#pragma unroll
  for (int i = 0; i < 4; ++i) {
    const float inv = 0.125f / cs[d0 + i];   // 1/(sqrt(64)*colsum)
#pragma unroll
    for (int j = 0; j < 4; ++j) {
      float s = 0;
      for (int c = 0; c < 8; ++c)
        s += Upart[((size_t)(c * 64 + nh) * 64 + d0 + i) * 64 + e0 + j];
      ctxT[((size_t)nh * 64 + (e0 + j)) * 64 + (d0 + i)] = f2bf(s * inv);
    }
  }
}

// ---------------------------------------------------------------- out: softmax_feat(qp) @ ctx via MFMA
// grid (64 t-tiles of 128, 64 nh), 256 threads (4 waves x 32 rows)
__global__ __launch_bounds__(256) void outk(
    const unsigned short* __restrict__ Pq,
    const unsigned short* __restrict__ ctxT,
    float* __restrict__ Out) {
  const int tb = blockIdx.x;
  const int nh = blockIdx.y;
  const int n = nh >> 4, h = nh & 15;
  const int tid = threadIdx.x, lane = tid & 63, wid = tid >> 6;
  __shared__ unsigned short sp[128][72];   // padded: row stride 144 B

  // B fragments (ctx^T) straight from global, K=64 -> 2 k-steps x 4 n-tiles
  bf16x8 breg[2][4];
#pragma unroll
  for (int ks = 0; ks < 2; ++ks)
#pragma unroll
    for (int nn = 0; nn < 4; ++nn)
      breg[ks][nn] = *(const bf16x8*)(ctxT + ((size_t)nh * 64 + nn * 16 + (lane & 15)) * 64
                                      + ks * 32 + (lane >> 4) * 8);

  // stage: thread handles row r = tid>>1, half = tid&1 (32 features)
  const int r = tid >> 1, half = tid & 1;
  const int t0 = tb * 128;
  const size_t qoff = (size_t)(n * T_ + t0 + r) * H_ + h * DH + half * 32;
  u16x8 qv[4];
#pragma unroll
  for (int s = 0; s < 4; ++s) qv[s] = *(const u16x8*)(Pq + qoff + s * 8);
  float e[32]; float sum = 0.f;
#pragma unroll
  for (int s = 0; s < 4; ++s)
#pragma unroll
    for (int j = 0; j < 8; ++j) { float x = __expf(bf2f(qv[s][j])); e[s * 8 + j] = x; sum += x; }
  sum += __shfl_xor(sum, 1);               // full 64-feature row sum
  const float inv = 1.f / sum;
#pragma unroll
  for (int s = 0; s < 4; ++s) {
    u16x8 pb;
#pragma unroll
    for (int j = 0; j < 8; ++j) pb[j] = f2bf(e[s * 8 + j] * inv);
    *(u16x8*)&sp[r][half * 32 + s * 8] = pb;
  }
  __syncthreads();

  f32x4 acc[2][4];
  f32x4 z = {0.f, 0.f, 0.f, 0.f};
#pragma unroll
  for (int mm = 0; mm < 2; ++mm)
#pragma unroll
    for (int nn = 0; nn < 4; ++nn) acc[mm][nn] = z;
  const int wm = wid * 32;
#pragma unroll
  for (int ks = 0; ks < 2; ++ks) {
    bf16x8 av[2];
#pragma unroll
    for (int mm = 0; mm < 2; ++mm)
      av[mm] = *(const bf16x8*)((const char*)&sp[0][0]
               + (wm + mm * 16 + (lane & 15)) * 144 + ks * 64 + (lane >> 4) * 16);
#pragma unroll
    for (int mm = 0; mm < 2; ++mm)
#pragma unroll
      for (int nn = 0; nn < 4; ++nn)
        acc[mm][nn] = __builtin_amdgcn_mfma_f32_16x16x32_bf16(av[mm], breg[ks][nn], acc[mm][nn], 0, 0, 0);
  }

#pragma unroll
  for (int mm = 0; mm < 2; ++mm)
#pragma unroll
    for (int j = 0; j < 4; ++j) {
      const int row = t0 + wm + mm * 16 + (lane >> 4) * 4 + j;
      float* op = Out + ((size_t)n * T_ + row) * H_ + h * DH + (lane & 15);
#pragma unroll
      for (int nn = 0; nn < 4; ++nn) op[nn * 16] = acc[mm][nn][j];
    }
}

// ---------------------------------------------------------------- launch
extern "C" void kernel_launch(void* const* d_in, const int* in_sizes, int n_in,
                              void* d_out, int out_size, void* d_ws, size_t ws_size,
                              hipStream_t stream) {
  const float* q  = (const float*)d_in[0];
  const float* k  = (const float*)d_in[1];
  const float* v  = (const float*)d_in[2];
  // d_in[3] = mask_q: per-row constant before feature-dim softmax -> provably a no-op
  const float* mask_attn = (const float*)d_in[4];
  const float* Wq = (const float*)d_in[5];
  const float* bq = (const float*)d_in[6];
  const float* Wk = (const float*)d_in[7];
  const float* bk = (const float*)d_in[8];
  const float* Wv = (const float*)d_in[9];
  const float* bv = (const float*)d_in[10];
  float* out = (float*)d_out;

  char* ws = (char*)d_ws;
  size_t off = 0;
  unsigned short* Xb = (unsigned short*)(ws + off); off += (size_t)BT * H_ * 2;       // 64 MB
  unsigned short* Wb = (unsigned short*)(ws + off); off += (size_t)3 * H_ * H_ * 2;   // 6 MB
  unsigned short* Pq = (unsigned short*)(ws + off); off += (size_t)BT * H_ * 2;
  unsigned short* Pk = (unsigned short*)(ws + off); off += (size_t)BT * H_ * 2;
  unsigned short* Pv = (unsigned short*)(ws + off); off += (size_t)BT * H_ * 2;
  float* Upart  = (float*)(ws + off); off += (size_t)8 * 64 * 64 * 64 * 4;            // 8 MB
  float* cspart = (float*)(ws + off); off += (size_t)8 * 64 * 64 * 4;
  unsigned short* ctxT = (unsigned short*)(ws + off); off += (size_t)64 * 64 * 64 * 2;

  dim3 blk(256);
  const int nW4 = H_ * H_ / 4;
  cvt_kernel<<<dim3(512), blk, 0, stream>>>(Wq, Wb + 0 * H_ * H_, nW4);
  cvt_kernel<<<dim3(512), blk, 0, stream>>>(Wk, Wb + 1 * H_ * H_, nW4);
  cvt_kernel<<<dim3(512), blk, 0, stream>>>(Wv, Wb + 2 * H_ * H_, nW4);

  const int nX4 = BT * H_ / 4;
  dim3 ggrid(8, 256);   // N/128, M/128 (gemm_nt swizzle assumes this shape)
  cvt_kernel<<<dim3(2048), blk, 0, stream>>>(k, Xb, nX4);
  gemm_nt<<<ggrid, blk, 0, stream>>>(Xb, Wb + 1 * H_ * H_, bk, Pk);
  cvt_kernel<<<dim3(2048), blk, 0, stream>>>(v, Xb, nX4);
  gemm_nt<<<ggrid, blk, 0, stream>>>(Xb, Wb + 2 * H_ * H_, bv, Pv);
  cvt_kernel<<<dim3(2048), blk, 0, stream>>>(q, Xb, nX4);
  gemm_nt<<<ggrid, blk, 0, stream>>>(Xb, Wb + 0 * H_ * H_, bq, Pq);

  phase1<<<dim3(8, 64), blk, 0, stream>>>(Pk, Pv, mask_attn, Upart, cspart);
  ctxbuild<<<dim3(64), blk, 0, stream>>>(Upart, cspart, ctxT);
  outk<<<dim3(64, 64), blk, 0, stream>>>(Pq, ctxT, out);
}

// Round 4
// 417.819 us; speedup vs baseline: 1.3626x; 1.0698x over previous
//
#include <hip/hip_runtime.h>
#include <hip/hip_bf16.h>
#include <math.h>

// Problem constants
#define B_  4
#define T_  8192
#define H_  1024
#define NHEAD 16
#define DH  64
#define BT  (B_*T_)   // 32768 rows

typedef __attribute__((ext_vector_type(8))) short bf16x8;
typedef __attribute__((ext_vector_type(4))) float f32x4;
typedef __attribute__((ext_vector_type(2))) float f32x2;
typedef __attribute__((ext_vector_type(2))) unsigned short u16x2;
typedef __attribute__((ext_vector_type(4))) unsigned short u16x4;
typedef __attribute__((ext_vector_type(8))) unsigned short u16x8;

static __device__ __forceinline__ float bf2f(unsigned short u) {
  union { unsigned int i; float f; } x; x.i = ((unsigned int)u) << 16; return x.f;
}
static __device__ __forceinline__ unsigned short f2bf(float f) {
  union { float f; unsigned int i; } x; x.f = f;
  unsigned int r = x.i + 0x7fffu + ((x.i >> 16) & 1u);  // RNE
  return (unsigned short)(r >> 16);
}

#define GL2LDS(gptr, sptr) \
  __builtin_amdgcn_global_load_lds((const __attribute__((address_space(1))) void*)(gptr), \
                                   (__attribute__((address_space(3))) void*)(sptr), 16, 0, 0)

#define BAR() do { asm volatile("" ::: "memory"); __builtin_amdgcn_s_barrier(); \
                   asm volatile("" ::: "memory"); } while (0)

// ---------------------------------------------------------------- cvt fp32->bf16
__global__ void cvt_kernel(const float* __restrict__ in, unsigned short* __restrict__ out, int n4) {
  int i = blockIdx.x * blockDim.x + threadIdx.x;
  int stride = gridDim.x * blockDim.x;
  for (int idx = i; idx < n4; idx += stride) {
    float4 v = reinterpret_cast<const float4*>(in)[idx];
    u16x4 o;
    o.x = f2bf(v.x); o.y = f2bf(v.y); o.z = f2bf(v.z); o.w = f2bf(v.w);
    reinterpret_cast<u16x4*>(out)[idx] = o;
  }
}

// ---------------------------------------------------------------- 256x256 4-phase bf16 GEMM
// C[M,N] = A[M,K]*B[N,K]^T + bias ; M=32768, N=K=1024. BM=BN=256, BK=64,
// 8 waves (2M x 4N), per-wave 128x64 out. LDS 128 KiB = 2 K-tile buffers
// (A 32KB + B 32KB each). st_16x32 swizzle: linear LDS dest (gload_lds) +
// pre-swizzled global SOURCE + XOR'd read addr (involution byte^=((byte>>9)&1)<<5).
// LIVENESS (fixed r3 race): A region read by its wave in P1(mh0)+P3(mh1) ->
// whole A live to end-P3 -> restage A in P4. B read P1(nh0)+P2(nh1) ->
// restage B in P3. One counted vmcnt(8) per K-tile at end-P4: outstanding
// there = tile(t+1) 8 + tile(t+2) 8; drains t+1 exactly. Tail 14: vmcnt(0).
// grid = 512 blocks (128 Mtiles x 4 Ntiles), XCD-bijective swizzle (512%8==0).
__global__ __launch_bounds__(512, 2) void gemm256(
    const unsigned short* __restrict__ A,
    const unsigned short* __restrict__ Bm,
    const float* __restrict__ bias,
    unsigned short* __restrict__ C) {
  const int K = 1024, N = 1024;
  __shared__ char lds[131072];
  const int tid = threadIdx.x, lane = tid & 63, wid = tid >> 6;
  const int orig = blockIdx.x;
  const int swzb = (orig & 7) * 64 + (orig >> 3);
  const int bm = (swzb >> 2) * 256, bn = (swzb & 3) * 256;
  const int wm = wid >> 2, wn = wid & 3;

  // staging geometry: lane covers linear LDS bytes (wid*1024 + lane*16);
  // source fetches the element the SWIZZLED layout wants there.
  const int sr   = wid * 8 + (lane >> 3);                   // row within 64-row chunk
  const int scol = ((lane & 7) * 8) ^ ((lane & 32) >> 1);   // pre-swizzled col (elems)
  const unsigned short* gA = A  + (size_t)(bm + sr) * K + scol;
  const unsigned short* gB = Bm + (size_t)(bn + sr) * K + scol;
  const int dstw = wid * 1024;

  // fragment read geometry (swizzled): flat = row*128 + ks*64 + (lane>>4)*16,
  // XOR 32 iff bit9 of flat set <=> (row>>2)&1 <=> (lane&4).
  const int aflag = (lane & 4) ? 32 : 0;
  const int lcol  = ((lane >> 4) * 16) ^ aflag;
  const int aoff0 = (wm * 128 + (lane & 15)) * 128 + lcol;
  const int boff0 = 32768 + (wn * 64 + (lane & 15)) * 128 + lcol;

  f32x4 acc[8][4];
#pragma unroll
  for (int fn = 0; fn < 4; ++fn) {
    float bv = bias[bn + wn * 64 + fn * 16 + (lane & 15)];
    f32x4 sp = {bv, bv, bv, bv};
#pragma unroll
    for (int fm = 0; fm < 8; ++fm) acc[fm][fn] = sp;
  }

  bf16x8 aF[4][2], bF[4][2];

  auto stA4 = [&](int buf, int kt) {                 // full A tile: 4 gloads
    char* d = lds + buf * 65536 + dstw;
    const unsigned short* g = gA + kt * 64;
    GL2LDS(g, d);
    GL2LDS(g + (size_t)64  * K, d + 8192);
    GL2LDS(g + (size_t)128 * K, d + 16384);
    GL2LDS(g + (size_t)192 * K, d + 24576);
  };
  auto stB = [&](int buf, int kt) {                  // full B tile: 4 gloads
    char* d = lds + buf * 65536 + 32768 + dstw;
    const unsigned short* g = gB + kt * 64;
    GL2LDS(g, d);
    GL2LDS(g + (size_t)64  * K, d + 8192);
    GL2LDS(g + (size_t)128 * K, d + 16384);
    GL2LDS(g + (size_t)192 * K, d + 24576);
  };
  auto loadA = [&](int buf, int mh) {
#pragma unroll
    for (int f = 0; f < 4; ++f)
#pragma unroll
      for (int ks = 0; ks < 2; ++ks)
        aF[f][ks] = *(const bf16x8*)(lds + buf * 65536 + aoff0 + (mh * 4 + f) * 2048 + ks * 64);
  };
  auto loadB = [&](int buf, int nh) {
#pragma unroll
    for (int f = 0; f < 2; ++f)
#pragma unroll
      for (int ks = 0; ks < 2; ++ks)
        bF[nh * 2 + f][ks] = *(const bf16x8*)(lds + buf * 65536 + boff0 + (nh * 2 + f) * 2048 + ks * 64);
  };
  auto quad = [&](int mh, int nh) {                  // 16 MFMA cluster (T5 setprio)
    __builtin_amdgcn_s_setprio(1);
#pragma unroll
    for (int f = 0; f < 4; ++f)
#pragma unroll
      for (int g2 = 0; g2 < 2; ++g2)
#pragma unroll
        for (int ks = 0; ks < 2; ++ks)
          acc[mh * 4 + f][nh * 2 + g2] = __builtin_amdgcn_mfma_f32_16x16x32_bf16(
              aF[f][ks], bF[nh * 2 + g2][ks], acc[mh * 4 + f][nh * 2 + g2], 0, 0, 0);
    __builtin_amdgcn_s_setprio(0);
  };

  // prologue: stage K-tiles 0 and 1 (tile0's 8 issues precede tile1's 8)
  stA4(0, 0); stB(0, 0);
  stA4(1, 1); stB(1, 1);
  asm volatile("s_waitcnt vmcnt(8)" ::: "memory");   // K-tile 0 fully landed
  BAR();

#define KTILE(t, STG, WSTR, DOW)                              \
  {                                                           \
    const int b_ = (t) & 1;                                   \
    loadA(b_, 0); loadB(b_, 0);                               \
    quad(0, 0);                                               \
    BAR();                                                    \
    loadB(b_, 1);                                             \
    quad(0, 1);                                               \
    BAR();                                                    \
    if (STG) stB(b_, (t) + 2);                                \
    loadA(b_, 1);                                             \
    quad(1, 0);                                               \
    BAR();                                                    \
    if (STG) stA4(b_, (t) + 2);                               \
    quad(1, 1);                                               \
    if (DOW) { asm volatile("s_waitcnt vmcnt(" WSTR ")" ::: "memory"); } \
    BAR();                                                    \
  }

  for (int t = 0; t < 14; ++t) KTILE(t, 1, "8", 1)
  KTILE(14, 0, "0", 1)
  KTILE(15, 0, "0", 0)
#undef KTILE

  // epilogue: C write
  const int crow0 = bm + wm * 128 + (lane >> 4) * 4;
  const int ccol0 = bn + wn * 64 + (lane & 15);
#pragma unroll
  for (int fm = 0; fm < 8; ++fm)
#pragma unroll
    for (int j = 0; j < 4; ++j) {
      unsigned short* cp = C + (size_t)(crow0 + fm * 16 + j) * N + ccol0;
#pragma unroll
      for (int fn = 0; fn < 4; ++fn) cp[fn * 16] = f2bf(acc[fm][fn][j]);
    }
}

// ---------------------------------------------------------------- phase1 (MFMA): U-partials + colsum
__global__ __launch_bounds__(256, 2) void phase1(
    const unsigned short* __restrict__ Pk,
    const unsigned short* __restrict__ Pv,
    const float* __restrict__ mask_attn,
    float* __restrict__ Upart,     // [8][64][64][64]
    float* __restrict__ cspart) {  // [8][64][64]
  const int chunk = blockIdx.x;
  const int nh = blockIdx.y;
  const int n = nh >> 4, h = nh & 15;
  const int tid = threadIdx.x, lane = tid & 63, wid = tid >> 6;
  __shared__ __align__(16) unsigned short ekT[64 * 256];  // 32 KB
  __shared__ __align__(16) unsigned short vpT[64 * 256];  // 32 KB

  f32x4 acc[5];
#pragma unroll
  for (int i = 0; i < 5; ++i) acc[i] = (f32x4){0.f, 0.f, 0.f, 0.f};
  bf16x8 ones;
#pragma unroll
  for (int j = 0; j < 8; ++j) ones[j] = (short)0x3f80;

  const int isV = tid >> 7;
  const int slot0 = tid & 127;
  const unsigned short* src = isV ? Pv : Pk;
  unsigned short* dstT = isV ? vpT : ekT;

  const int arow = wid * 16 + (lane & 15);
  const int aswz = ((arow & 7) ^ ((arow >> 3) & 7)) << 4;

  for (int stage = 0; stage < 4; ++stage) {
    if (stage) __syncthreads();
#pragma unroll
    for (int r = 0; r < 2; ++r) {
      const int slot = slot0 + r * 128;
      const int toct = slot >> 3;
      const int d0   = (slot & 7) * 8;
      const int tbase = chunk * 1024 + stage * 256 + toct * 8;
      u16x8 in[8];
#pragma unroll
      for (int s = 0; s < 8; ++s)
        in[s] = *(const u16x8*)(src + (size_t)(n * T_ + tbase + s) * H_ + h * DH + d0);
      if (!isV) {
#pragma unroll
        for (int s = 0; s < 8; ++s) {
          const float madd = -10000.f * (1.f - mask_attn[n * T_ + tbase + s]);
          u16x8 o;
#pragma unroll
          for (int j = 0; j < 8; ++j) o[j] = f2bf(__expf(bf2f(in[s][j]) + madd));
          in[s] = o;
        }
      }
#pragma unroll
      for (int i = 0; i < 8; ++i) {
        u16x8 o;
#pragma unroll
        for (int s = 0; s < 8; ++s) o[s] = in[s][i];
        const int d = d0 + i;
        const int boff = (toct * 16) ^ (((d & 7) ^ ((d >> 3) & 7)) << 4);
        *(u16x8*)((char*)dstT + d * 512 + boff) = o;
      }
    }
    __syncthreads();
#pragma unroll
    for (int kk = 0; kk < 8; ++kk) {
      const int koff = kk * 64 + (lane >> 4) * 16;
      bf16x8 af = *(const bf16x8*)((const char*)ekT + arow * 512 + (koff ^ aswz));
      acc[4] = __builtin_amdgcn_mfma_f32_16x16x32_bf16(af, ones, acc[4], 0, 0, 0);
#pragma unroll
      for (int nn = 0; nn < 4; ++nn) {
        const int brow = nn * 16 + (lane & 15);
        const int bswz = ((brow & 7) ^ ((brow >> 3) & 7)) << 4;
        bf16x8 bf_ = *(const bf16x8*)((const char*)vpT + brow * 512 + (koff ^ bswz));
        acc[nn] = __builtin_amdgcn_mfma_f32_16x16x32_bf16(af, bf_, acc[nn], 0, 0, 0);
      }
    }
  }

  const int d = wid * 16 + (lane >> 4) * 4;
  const int e = lane & 15;
  float* up = Upart + ((size_t)(chunk * 64 + nh) * 64) * 64;
#pragma unroll
  for (int nn = 0; nn < 4; ++nn)
#pragma unroll
    for (int j = 0; j < 4; ++j)
      up[(size_t)(d + j) * 64 + nn * 16 + e] = acc[nn][j];
  if (e == 0)
#pragma unroll
    for (int j = 0; j < 4; ++j)
      cspart[((size_t)chunk * 64 + nh) * 64 + d + j] = acc[4][j];
}

// ---------------------------------------------------------------- ctx build
__global__ void ctxbuild(const float* __restrict__ Upart,
                         const float* __restrict__ cspart,
                         unsigned short* __restrict__ ctxT) {  // [64 nh][64 e][64 d]
  const int nh = blockIdx.x, tid = threadIdx.x;
  __shared__ float cs[64];
  if (tid < 64) {
    float s = 0;
    for (int c = 0; c < 8; ++c) s += cspart[((size_t)c * 64 + nh) * 64 + tid];
    cs[tid] = s;
  }
  __syncthreads();
  const int d0 = (tid >> 4) * 4, e0 = (tid & 15) * 4;
#pragma unroll
  for (int i = 0; i < 4; ++i) {
    const float inv = 0.125f / cs[d0 + i];   // 1/(sqrt(64)*colsum)
#pragma unroll
    for (int j = 0; j < 4; ++j) {
      float s = 0;
      for (int c = 0; c < 8; ++c)
        s += Upart[((size_t)(c * 64 + nh) * 64 + d0 + i) * 64 + e0 + j];
      ctxT[((size_t)nh * 64 + (e0 + j)) * 64 + (d0 + i)] = f2bf(s * inv);
    }
  }
}

// ---------------------------------------------------------------- out: softmax_feat(qp) @ ctx
__global__ __launch_bounds__(256) void outk(
    const unsigned short* __restrict__ Pq,
    const unsigned short* __restrict__ ctxT,
    float* __restrict__ Out) {
  const int tb = blockIdx.x;
  const int nh = blockIdx.y;
  const int n = nh >> 4, h = nh & 15;
  const int tid = threadIdx.x, lane = tid & 63, wid = tid >> 6;
  __shared__ unsigned short sp[128][72];

  bf16x8 breg[2][4];
#pragma unroll
  for (int ks = 0; ks < 2; ++ks)
#pragma unroll
    for (int nn = 0; nn < 4; ++nn)
      breg[ks][nn] = *(const bf16x8*)(ctxT + ((size_t)nh * 64 + nn * 16 + (lane & 15)) * 64
                                      + ks * 32 + (lane >> 4) * 8);

  const int r = tid >> 1, half = tid & 1;
  const int t0 = tb * 128;
  const size_t qoff = (size_t)(n * T_ + t0 + r) * H_ + h * DH + half * 32;
  u16x8 qv[4];
#pragma unroll
  for (int s = 0; s < 4; ++s) qv[s] = *(const u16x8*)(Pq + qoff + s * 8);
  float e[32]; float sum = 0.f;
#pragma unroll
  for (int s = 0; s < 4; ++s)
#pragma unroll
    for (int j = 0; j < 8; ++j) { float x = __expf(bf2f(qv[s][j])); e[s * 8 + j] = x; sum += x; }
  sum += __shfl_xor(sum, 1);
  const float inv = 1.f / sum;
#pragma unroll
  for (int s = 0; s < 4; ++s) {
    u16x8 pb;
#pragma unroll
    for (int j = 0; j < 8; ++j) pb[j] = f2bf(e[s * 8 + j] * inv);
    *(u16x8*)&sp[r][half * 32 + s * 8] = pb;
  }
  __syncthreads();

  f32x4 acc[2][4];
  f32x4 z = {0.f, 0.f, 0.f, 0.f};
#pragma unroll
  for (int mm = 0; mm < 2; ++mm)
#pragma unroll
    for (int nn = 0; nn < 4; ++nn) acc[mm][nn] = z;
  const int wm = wid * 32;
#pragma unroll
  for (int ks = 0; ks < 2; ++ks) {
    bf16x8 av[2];
#pragma unroll
    for (int mm = 0; mm < 2; ++mm)
      av[mm] = *(const bf16x8*)((const char*)&sp[0][0]
               + (wm + mm * 16 + (lane & 15)) * 144 + ks * 64 + (lane >> 4) * 16);
#pragma unroll
    for (int mm = 0; mm < 2; ++mm)
#pragma unroll
      for (int nn = 0; nn < 4; ++nn)
        acc[mm][nn] = __builtin_amdgcn_mfma_f32_16x16x32_bf16(av[mm], breg[ks][nn], acc[mm][nn], 0, 0, 0);
  }

#pragma unroll
  for (int mm = 0; mm < 2; ++mm)
#pragma unroll
    for (int j = 0; j < 4; ++j) {
      const int row = t0 + wm + mm * 16 + (lane >> 4) * 4 + j;
      float* op = Out + ((size_t)n * T_ + row) * H_ + h * DH + (lane & 15);
#pragma unroll
      for (int nn = 0; nn < 4; ++nn) op[nn * 16] = acc[mm][nn][j];
    }
}

// ---------------------------------------------------------------- launch
extern "C" void kernel_launch(void* const* d_in, const int* in_sizes, int n_in,
                              void* d_out, int out_size, void* d_ws, size_t ws_size,
                              hipStream_t stream) {
  const float* q  = (const float*)d_in[0];
  const float* k  = (const float*)d_in[1];
  const float* v  = (const float*)d_in[2];
  // d_in[3] = mask_q: per-row constant before feature-dim softmax -> provably a no-op
  const float* mask_attn = (const float*)d_in[4];
  const float* Wq = (const float*)d_in[5];
  const float* bq = (const float*)d_in[6];
  const float* Wk = (const float*)d_in[7];
  const float* bk = (const float*)d_in[8];
  const float* Wv = (const float*)d_in[9];
  const float* bv = (const float*)d_in[10];
  float* out = (float*)d_out;

  char* ws = (char*)d_ws;
  size_t off = 0;
  unsigned short* Xb = (unsigned short*)(ws + off); off += (size_t)BT * H_ * 2;       // 64 MB
  unsigned short* Wb = (unsigned short*)(ws + off); off += (size_t)3 * H_ * H_ * 2;   // 6 MB
  unsigned short* Pq = (unsigned short*)(ws + off); off += (size_t)BT * H_ * 2;
  unsigned short* Pk = (unsigned short*)(ws + off); off += (size_t)BT * H_ * 2;
  unsigned short* Pv = (unsigned short*)(ws + off); off += (size_t)BT * H_ * 2;
  float* Upart  = (float*)(ws + off); off += (size_t)8 * 64 * 64 * 64 * 4;            // 8 MB
  float* cspart = (float*)(ws + off); off += (size_t)8 * 64 * 64 * 4;
  unsigned short* ctxT = (unsigned short*)(ws + off); off += (size_t)64 * 64 * 64 * 2;

  dim3 blk(256);
  const int nW4 = H_ * H_ / 4;
  cvt_kernel<<<dim3(512), blk, 0, stream>>>(Wq, Wb + 0 * H_ * H_, nW4);
  cvt_kernel<<<dim3(512), blk, 0, stream>>>(Wk, Wb + 1 * H_ * H_, nW4);
  cvt_kernel<<<dim3(512), blk, 0, stream>>>(Wv, Wb + 2 * H_ * H_, nW4);

  const int nX4 = BT * H_ / 4;
  dim3 gblk(512);
  dim3 ggrid(512);   // 128 Mtiles x 4 Ntiles
  cvt_kernel<<<dim3(2048), blk, 0, stream>>>(k, Xb, nX4);
  gemm256<<<ggrid, gblk, 0, stream>>>(Xb, Wb + 1 * H_ * H_, bk, Pk);
  cvt_kernel<<<dim3(2048), blk, 0, stream>>>(v, Xb, nX4);
  gemm256<<<ggrid, gblk, 0, stream>>>(Xb, Wb + 2 * H_ * H_, bv, Pv);
  cvt_kernel<<<dim3(2048), blk, 0, stream>>>(q, Xb, nX4);
  gemm256<<<ggrid, gblk, 0, stream>>>(Xb, Wb + 0 * H_ * H_, bq, Pq);

  phase1<<<dim3(8, 64), blk, 0, stream>>>(Pk, Pv, mask_attn, Upart, cspart);
  ctxbuild<<<dim3(64), blk, 0, stream>>>(Upart, cspart, ctxT);
  outk<<<dim3(64, 64), blk, 0, stream>>>(Pq, ctxT, out);
}

// Round 5
// 410.502 us; speedup vs baseline: 1.3869x; 1.0178x over previous
//
#include <hip/hip_runtime.h>
#include <hip/hip_bf16.h>
#include <math.h>

// Problem constants
#define B_  4
#define T_  8192
#define H_  1024
#define NHEAD 16
#define DH  64
#define BT  (B_*T_)   // 32768 rows

typedef __attribute__((ext_vector_type(8))) short bf16x8;
typedef __attribute__((ext_vector_type(4))) float f32x4;
typedef __attribute__((ext_vector_type(2))) float f32x2;
typedef __attribute__((ext_vector_type(2))) unsigned short u16x2;
typedef __attribute__((ext_vector_type(4))) unsigned short u16x4;
typedef __attribute__((ext_vector_type(8))) unsigned short u16x8;

static __device__ __forceinline__ float bf2f(unsigned short u) {
  union { unsigned int i; float f; } x; x.i = ((unsigned int)u) << 16; return x.f;
}
static __device__ __forceinline__ unsigned short f2bf(float f) {
  union { float f; unsigned int i; } x; x.f = f;
  unsigned int r = x.i + 0x7fffu + ((x.i >> 16) & 1u);  // RNE
  return (unsigned short)(r >> 16);
}

#define GL2LDS(gptr, sptr) \
  __builtin_amdgcn_global_load_lds((const __attribute__((address_space(1))) void*)(gptr), \
                                   (__attribute__((address_space(3))) void*)(sptr), 16, 0, 0)

#define BAR() do { asm volatile("" ::: "memory"); __builtin_amdgcn_s_barrier(); \
                   asm volatile("" ::: "memory"); } while (0)

// ---------------------------------------------------------------- cvt fp32->bf16
__global__ void cvt_kernel(const float* __restrict__ in, unsigned short* __restrict__ out, int n4) {
  int i = blockIdx.x * blockDim.x + threadIdx.x;
  int stride = gridDim.x * blockDim.x;
  for (int idx = i; idx < n4; idx += stride) {
    float4 v = reinterpret_cast<const float4*>(in)[idx];
    u16x4 o;
    o.x = f2bf(v.x); o.y = f2bf(v.y); o.z = f2bf(v.z); o.w = f2bf(v.w);
    reinterpret_cast<u16x4*>(out)[idx] = o;
  }
}

// ---------------------------------------------------------------- 256x256 4-phase bf16 GEMM
// C[M,N] = A[M,K]*B[N,K]^T + bias ; M=32768, N=K=1024. BM=BN=256, BK=64,
// 8 waves (2M x 4N), per-wave 128x64 out. LDS 128 KiB = 2 K-tile buffers.
// SWIZZLE (r4 fix): full-depth XOR byte ^= ((row&7)<<4) (G4 pattern).
// 16 lanes reading 16 rows at one 16B col now spread over 8 slots = all 32
// banks, 2 lanes/bank (free). Involution applied as: linear gload_lds dest +
// pre-swizzled global SOURCE col + XOR'd read col (rule #21).
// LIVENESS: whole A live to end-P3 -> restage A in P4; B live to end-P2 ->
// restage B in P3. One counted vmcnt(8) per K-tile at end-P4 (drains t+1).
// grid = 512 blocks, XCD-bijective swizzle (512%8==0).
__global__ __launch_bounds__(512, 2) void gemm256(
    const unsigned short* __restrict__ A,
    const unsigned short* __restrict__ Bm,
    const float* __restrict__ bias,
    unsigned short* __restrict__ C) {
  const int K = 1024, N = 1024;
  __shared__ char lds[131072];
  const int tid = threadIdx.x, lane = tid & 63, wid = tid >> 6;
  const int orig = blockIdx.x;
  const int swzb = (orig & 7) * 64 + (orig >> 3);
  const int bm = (swzb >> 2) * 256, bn = (swzb & 3) * 256;
  const int wm = wid >> 2, wn = wid & 3;

  // staging: lane covers linear LDS bytes (wid*1024 + lane*16) of a 64-row
  // chunk; that linear slot is row sr=(wid*8+lane>>3), colbyte (lane&7)*16.
  // Swizzled layout wants source colbyte ((lane&7)*16) ^ ((sr&7)<<4), and
  // sr&7 = lane>>3  ->  scol elems = ((lane&7)*8) ^ ((lane>>3)<<3).
  const int sr   = wid * 8 + (lane >> 3);
  const int scol = ((lane & 7) * 8) ^ ((lane >> 3) << 3);
  const unsigned short* gA = A  + (size_t)(bm + sr) * K + scol;
  const unsigned short* gB = Bm + (size_t)(bn + sr) * K + scol;
  const int dstw = wid * 1024;

  // fragment read: row = (tilebase + lane&15), row&7 = lane&7 (all other
  // terms are multiples of 16). col = ((lane>>4)*16 + ks*64) ^ ((lane&7)<<4)
  // -- full XOR on the combined k-offset (bits 4..6 all participate).
  const int aswz  = (lane & 7) << 4;
  const int arow0 = (wm * 128 + (lane & 15)) * 128;            // A row-base bytes
  const int brow0 = 32768 + (wn * 64 + (lane & 15)) * 128;     // B row-base bytes

  f32x4 acc[8][4];
#pragma unroll
  for (int fn = 0; fn < 4; ++fn) {
    float bv = bias[bn + wn * 64 + fn * 16 + (lane & 15)];
    f32x4 sp = {bv, bv, bv, bv};
#pragma unroll
    for (int fm = 0; fm < 8; ++fm) acc[fm][fn] = sp;
  }

  bf16x8 aF[4][2], bF[4][2];

  auto stA4 = [&](int buf, int kt) {                 // full A tile: 4 gloads
    char* d = lds + buf * 65536 + dstw;
    const unsigned short* g = gA + kt * 64;
    GL2LDS(g, d);
    GL2LDS(g + (size_t)64  * K, d + 8192);
    GL2LDS(g + (size_t)128 * K, d + 16384);
    GL2LDS(g + (size_t)192 * K, d + 24576);
  };
  auto stB = [&](int buf, int kt) {                  // full B tile: 4 gloads
    char* d = lds + buf * 65536 + 32768 + dstw;
    const unsigned short* g = gB + kt * 64;
    GL2LDS(g, d);
    GL2LDS(g + (size_t)64  * K, d + 8192);
    GL2LDS(g + (size_t)128 * K, d + 16384);
    GL2LDS(g + (size_t)192 * K, d + 24576);
  };
  auto loadA = [&](int buf, int mh) {
#pragma unroll
    for (int f = 0; f < 4; ++f)
#pragma unroll
      for (int ks = 0; ks < 2; ++ks)
        aF[f][ks] = *(const bf16x8*)(lds + buf * 65536 + arow0 + (mh * 4 + f) * 2048
                                     + (((lane >> 4) * 16 + ks * 64) ^ aswz));
  };
  auto loadB = [&](int buf, int nh) {
#pragma unroll
    for (int f = 0; f < 2; ++f)
#pragma unroll
      for (int ks = 0; ks < 2; ++ks)
        bF[nh * 2 + f][ks] = *(const bf16x8*)(lds + buf * 65536 + brow0 + (nh * 2 + f) * 2048
                                              + (((lane >> 4) * 16 + ks * 64) ^ aswz));
  };
  auto quad = [&](int mh, int nh) {                  // 16 MFMA cluster (T5 setprio)
    __builtin_amdgcn_s_setprio(1);
#pragma unroll
    for (int f = 0; f < 4; ++f)
#pragma unroll
      for (int g2 = 0; g2 < 2; ++g2)
#pragma unroll
        for (int ks = 0; ks < 2; ++ks)
          acc[mh * 4 + f][nh * 2 + g2] = __builtin_amdgcn_mfma_f32_16x16x32_bf16(
              aF[f][ks], bF[nh * 2 + g2][ks], acc[mh * 4 + f][nh * 2 + g2], 0, 0, 0);
    __builtin_amdgcn_s_setprio(0);
  };

  // prologue: stage K-tiles 0 and 1 (tile0's 8 issues precede tile1's 8)
  stA4(0, 0); stB(0, 0);
  stA4(1, 1); stB(1, 1);
  asm volatile("s_waitcnt vmcnt(8)" ::: "memory");   // K-tile 0 fully landed
  BAR();

#define KTILE(t, STG, WSTR, DOW)                              \
  {                                                           \
    const int b_ = (t) & 1;                                   \
    loadA(b_, 0); loadB(b_, 0);                               \
    quad(0, 0);                                               \
    BAR();                                                    \
    loadB(b_, 1);                                             \
    quad(0, 1);                                               \
    BAR();                                                    \
    if (STG) stB(b_, (t) + 2);                                \
    loadA(b_, 1);                                             \
    quad(1, 0);                                               \
    BAR();                                                    \
    if (STG) stA4(b_, (t) + 2);                               \
    quad(1, 1);                                               \
    if (DOW) { asm volatile("s_waitcnt vmcnt(" WSTR ")" ::: "memory"); } \
    BAR();                                                    \
  }

  for (int t = 0; t < 14; ++t) KTILE(t, 1, "8", 1)
  KTILE(14, 0, "0", 1)
  KTILE(15, 0, "0", 0)
#undef KTILE

  // epilogue: C write
  const int crow0 = bm + wm * 128 + (lane >> 4) * 4;
  const int ccol0 = bn + wn * 64 + (lane & 15);
#pragma unroll
  for (int fm = 0; fm < 8; ++fm)
#pragma unroll
    for (int j = 0; j < 4; ++j) {
      unsigned short* cp = C + (size_t)(crow0 + fm * 16 + j) * N + ccol0;
#pragma unroll
      for (int fn = 0; fn < 4; ++fn) cp[fn * 16] = f2bf(acc[fm][fn][j]);
    }
}

// ---------------------------------------------------------------- phase1 (MFMA): U-partials + colsum
__global__ __launch_bounds__(256, 2) void phase1(
    const unsigned short* __restrict__ Pk,
    const unsigned short* __restrict__ Pv,
    const float* __restrict__ mask_attn,
    float* __restrict__ Upart,     // [8][64][64][64]
    float* __restrict__ cspart) {  // [8][64][64]
  const int chunk = blockIdx.x;
  const int nh = blockIdx.y;
  const int n = nh >> 4, h = nh & 15;
  const int tid = threadIdx.x, lane = tid & 63, wid = tid >> 6;
  __shared__ __align__(16) unsigned short ekT[64 * 256];  // 32 KB
  __shared__ __align__(16) unsigned short vpT[64 * 256];  // 32 KB

  f32x4 acc[5];
#pragma unroll
  for (int i = 0; i < 5; ++i) acc[i] = (f32x4){0.f, 0.f, 0.f, 0.f};
  bf16x8 ones;
#pragma unroll
  for (int j = 0; j < 8; ++j) ones[j] = (short)0x3f80;

  const int isV = tid >> 7;
  const int slot0 = tid & 127;
  const unsigned short* src = isV ? Pv : Pk;
  unsigned short* dstT = isV ? vpT : ekT;

  const int arow = wid * 16 + (lane & 15);
  const int aswz = ((arow & 7) ^ ((arow >> 3) & 7)) << 4;

  for (int stage = 0; stage < 4; ++stage) {
    if (stage) __syncthreads();
#pragma unroll
    for (int r = 0; r < 2; ++r) {
      const int slot = slot0 + r * 128;
      const int toct = slot >> 3;
      const int d0   = (slot & 7) * 8;
      const int tbase = chunk * 1024 + stage * 256 + toct * 8;
      u16x8 in[8];
#pragma unroll
      for (int s = 0; s < 8; ++s)
        in[s] = *(const u16x8*)(src + (size_t)(n * T_ + tbase + s) * H_ + h * DH + d0);
      if (!isV) {
#pragma unroll
        for (int s = 0; s < 8; ++s) {
          const float madd = -10000.f * (1.f - mask_attn[n * T_ + tbase + s]);
          u16x8 o;
#pragma unroll
          for (int j = 0; j < 8; ++j) o[j] = f2bf(__expf(bf2f(in[s][j]) + madd));
          in[s] = o;
        }
      }
#pragma unroll
      for (int i = 0; i < 8; ++i) {
        u16x8 o;
#pragma unroll
        for (int s = 0; s < 8; ++s) o[s] = in[s][i];
        const int d = d0 + i;
        const int boff = (toct * 16) ^ (((d & 7) ^ ((d >> 3) & 7)) << 4);
        *(u16x8*)((char*)dstT + d * 512 + boff) = o;
      }
    }
    __syncthreads();
#pragma unroll
    for (int kk = 0; kk < 8; ++kk) {
      const int koff = kk * 64 + (lane >> 4) * 16;
      bf16x8 af = *(const bf16x8*)((const char*)ekT + arow * 512 + (koff ^ aswz));
      acc[4] = __builtin_amdgcn_mfma_f32_16x16x32_bf16(af, ones, acc[4], 0, 0, 0);
#pragma unroll
      for (int nn = 0; nn < 4; ++nn) {
        const int brow = nn * 16 + (lane & 15);
        const int bswz = ((brow & 7) ^ ((brow >> 3) & 7)) << 4;
        bf16x8 bf_ = *(const bf16x8*)((const char*)vpT + brow * 512 + (koff ^ bswz));
        acc[nn] = __builtin_amdgcn_mfma_f32_16x16x32_bf16(af, bf_, acc[nn], 0, 0, 0);
      }
    }
  }

  const int d = wid * 16 + (lane >> 4) * 4;
  const int e = lane & 15;
  float* up = Upart + ((size_t)(chunk * 64 + nh) * 64) * 64;
#pragma unroll
  for (int nn = 0; nn < 4; ++nn)
#pragma unroll
    for (int j = 0; j < 4; ++j)
      up[(size_t)(d + j) * 64 + nn * 16 + e] = acc[nn][j];
  if (e == 0)
#pragma unroll
    for (int j = 0; j < 4; ++j)
      cspart[((size_t)chunk * 64 + nh) * 64 + d + j] = acc[4][j];
}

// ---------------------------------------------------------------- ctx build
__global__ void ctxbuild(const float* __restrict__ Upart,
                         const float* __restrict__ cspart,
                         unsigned short* __restrict__ ctxT) {  // [64 nh][64 e][64 d]
  const int nh = blockIdx.x, tid = threadIdx.x;
  __shared__ float cs[64];
  if (tid < 64) {
    float s = 0;
    for (int c = 0; c < 8; ++c) s += cspart[((size_t)c * 64 + nh) * 64 + tid];
    cs[tid] = s;
  }
  __syncthreads();
  const int d0 = (tid >> 4) * 4, e0 = (tid & 15) * 4;
#pragma unroll
  for (int i = 0; i < 4; ++i) {
    const float inv = 0.125f / cs[d0 + i];   // 1/(sqrt(64)*colsum)
#pragma unroll
    for (int j = 0; j < 4; ++j) {
      float s = 0;
      for (int c = 0; c < 8; ++c)
        s += Upart[((size_t)(c * 64 + nh) * 64 + d0 + i) * 64 + e0 + j];
      ctxT[((size_t)nh * 64 + (e0 + j)) * 64 + (d0 + i)] = f2bf(s * inv);
    }
  }
}

// ---------------------------------------------------------------- out: softmax_feat(qp) @ ctx
__global__ __launch_bounds__(256) void outk(
    const unsigned short* __restrict__ Pq,
    const unsigned short* __restrict__ ctxT,
    float* __restrict__ Out) {
  const int tb = blockIdx.x;
  const int nh = blockIdx.y;
  const int n = nh >> 4, h = nh & 15;
  const int tid = threadIdx.x, lane = tid & 63, wid = tid >> 6;
  __shared__ unsigned short sp[128][72];

  bf16x8 breg[2][4];
#pragma unroll
  for (int ks = 0; ks < 2; ++ks)
#pragma unroll
    for (int nn = 0; nn < 4; ++nn)
      breg[ks][nn] = *(const bf16x8*)(ctxT + ((size_t)nh * 64 + nn * 16 + (lane & 15)) * 64
                                      + ks * 32 + (lane >> 4) * 8);

  const int r = tid >> 1, half = tid & 1;
  const int t0 = tb * 128;
  const size_t qoff = (size_t)(n * T_ + t0 + r) * H_ + h * DH + half * 32;
  u16x8 qv[4];
#pragma unroll
  for (int s = 0; s < 4; ++s) qv[s] = *(const u16x8*)(Pq + qoff + s * 8);
  float e[32]; float sum = 0.f;
#pragma unroll
  for (int s = 0; s < 4; ++s)
#pragma unroll
    for (int j = 0; j < 8; ++j) { float x = __expf(bf2f(qv[s][j])); e[s * 8 + j] = x; sum += x; }
  sum += __shfl_xor(sum, 1);
  const float inv = 1.f / sum;
#pragma unroll
  for (int s = 0; s < 4; ++s) {
    u16x8 pb;
#pragma unroll
    for (int j = 0; j < 8; ++j) pb[j] = f2bf(e[s * 8 + j] * inv);
    *(u16x8*)&sp[r][half * 32 + s * 8] = pb;
  }
  __syncthreads();

  f32x4 acc[2][4];
  f32x4 z = {0.f, 0.f, 0.f, 0.f};
#pragma unroll
  for (int mm = 0; mm < 2; ++mm)
#pragma unroll
    for (int nn = 0; nn < 4; ++nn) acc[mm][nn] = z;
  const int wm = wid * 32;
#pragma unroll
  for (int ks = 0; ks < 2; ++ks) {
    bf16x8 av[2];
#pragma unroll
    for (int mm = 0; mm < 2; ++mm)
      av[mm] = *(const bf16x8*)((const char*)&sp[0][0]
               + (wm + mm * 16 + (lane & 15)) * 144 + ks * 64 + (lane >> 4) * 16);
#pragma unroll
    for (int mm = 0; mm < 2; ++mm)
#pragma unroll
      for (int nn = 0; nn < 4; ++nn)
        acc[mm][nn] = __builtin_amdgcn_mfma_f32_16x16x32_bf16(av[mm], breg[ks][nn], acc[mm][nn], 0, 0, 0);
  }

#pragma unroll
  for (int mm = 0; mm < 2; ++mm)
#pragma unroll
    for (int j = 0; j < 4; ++j) {
      const int row = t0 + wm + mm * 16 + (lane >> 4) * 4 + j;
      float* op = Out + ((size_t)n * T_ + row) * H_ + h * DH + (lane & 15);
#pragma unroll
      for (int nn = 0; nn < 4; ++nn) op[nn * 16] = acc[mm][nn][j];
    }
}

// ---------------------------------------------------------------- launch
extern "C" void kernel_launch(void* const* d_in, const int* in_sizes, int n_in,
                              void* d_out, int out_size, void* d_ws, size_t ws_size,
                              hipStream_t stream) {
  const float* q  = (const float*)d_in[0];
  const float* k  = (const float*)d_in[1];
  const float* v  = (const float*)d_in[2];
  // d_in[3] = mask_q: per-row constant before feature-dim softmax -> provably a no-op
  const float* mask_attn = (const float*)d_in[4];
  const float* Wq = (const float*)d_in[5];
  const float* bq = (const float*)d_in[6];
  const float* Wk = (const float*)d_in[7];
  const float* bk = (const float*)d_in[8];
  const float* Wv = (const float*)d_in[9];
  const float* bv = (const float*)d_in[10];
  float* out = (float*)d_out;

  char* ws = (char*)d_ws;
  size_t off = 0;
  unsigned short* Xb = (unsigned short*)(ws + off); off += (size_t)BT * H_ * 2;       // 64 MB
  unsigned short* Wb = (unsigned short*)(ws + off); off += (size_t)3 * H_ * H_ * 2;   // 6 MB
  unsigned short* Pq = (unsigned short*)(ws + off); off += (size_t)BT * H_ * 2;
  unsigned short* Pk = (unsigned short*)(ws + off); off += (size_t)BT * H_ * 2;
  unsigned short* Pv = (unsigned short*)(ws + off); off += (size_t)BT * H_ * 2;
  float* Upart  = (float*)(ws + off); off += (size_t)8 * 64 * 64 * 64 * 4;            // 8 MB
  float* cspart = (float*)(ws + off); off += (size_t)8 * 64 * 64 * 4;
  unsigned short* ctxT = (unsigned short*)(ws + off); off += (size_t)64 * 64 * 64 * 2;

  dim3 blk(256);
  const int nW4 = H_ * H_ / 4;
  cvt_kernel<<<dim3(512), blk, 0, stream>>>(Wq, Wb + 0 * H_ * H_, nW4);
  cvt_kernel<<<dim3(512), blk, 0, stream>>>(Wk, Wb + 1 * H_ * H_, nW4);
  cvt_kernel<<<dim3(512), blk, 0, stream>>>(Wv, Wb + 2 * H_ * H_, nW4);

  const int nX4 = BT * H_ / 4;
  dim3 gblk(512);
  dim3 ggrid(512);   // 128 Mtiles x 4 Ntiles
  cvt_kernel<<<dim3(2048), blk, 0, stream>>>(k, Xb, nX4);
  gemm256<<<ggrid, gblk, 0, stream>>>(Xb, Wb + 1 * H_ * H_, bk, Pk);
  cvt_kernel<<<dim3(2048), blk, 0, stream>>>(v, Xb, nX4);
  gemm256<<<ggrid, gblk, 0, stream>>>(Xb, Wb + 2 * H_ * H_, bv, Pv);
  cvt_kernel<<<dim3(2048), blk, 0, stream>>>(q, Xb, nX4);
  gemm256<<<ggrid, gblk, 0, stream>>>(Xb, Wb + 0 * H_ * H_, bq, Pq);

  phase1<<<dim3(8, 64), blk, 0, stream>>>(Pk, Pv, mask_attn, Upart, cspart);
  ctxbuild<<<dim3(64), blk, 0, stream>>>(Upart, cspart, ctxT);
  outk<<<dim3(64, 64), blk, 0, stream>>>(Pq, ctxT, out);
}